// Round 11
// baseline (306.576 us; speedup 1.0000x reference)
//
#include <hip/hip_runtime.h>
#include <hip/hip_bf16.h>

// LightGCN layer: out = adj @ (x * (u >= 0.1) / 0.9)
// x: [16384,64] f32, adj: [16384,16384] f32, u: [16384,64] f32, out: [16384,64] f32
//
// Round 11: r10 (best, 205.8us) + ONE change: MT 16 -> 8, grid 2048 x 1-wave
// blocks = 8 independent streams/CU (was 4). Tests whether per-CU stream count
// limits DRAM smoothing. Each wave owns 8 rows over full K; the 16x16 MFMA
// computes rows 8-15 as duplicates (A-frag read uses r&7), only kg<2 stores.
// Schedule, counted-vmcnt ordering, nt A-loads, B-in-regs: identical to r10.

#define NN 16384
#define DD 64
#define MT 8
#define APH 256                // A-phase: K floats per staged chunk
#define NAPH (NN / APH)        // 64 A-phases
#define CHUNK 5120             // 4 sub-chunks x 1280 B (8 rows x 80B x 2 K-steps)

typedef __attribute__((ext_vector_type(4))) float floatx4;
typedef __attribute__((ext_vector_type(4))) short short4v;
typedef __attribute__((ext_vector_type(8))) short short8;

static __device__ __forceinline__ short bf16b(float f) {
    union { __hip_bfloat16 h; short s; } cv;
    cv.h = __float2bfloat16(f);
    return cv.s;
}

// B in MFMA fragment-linear order (unchanged, verified r1-r10):
// chunk c = s*256 + f*64 + lane; shorts at c*8:
// element j = B[s*32 + (lane>>4)*8 + j][f*16 + (lane&15)]
__global__ void __launch_bounds__(256) prep_kernel(const float* __restrict__ x,
                                                   const float* __restrict__ u,
                                                   short* __restrict__ bfrag) {
    int c = blockIdx.x * 256 + threadIdx.x;
    int lane = c & 63;
    int f = (c >> 6) & 3;
    int s = c >> 8;
    int col = f * 16 + (lane & 15);
    int k0 = s * 32 + (lane >> 4) * 8;
    short8 v;
#pragma unroll
    for (int j = 0; j < 8; ++j) {
        int idx = (k0 + j) * DD + col;
        float xv = x[idx];
        float uv = u[idx];
        float xd = (uv >= 0.1f) ? xv * (1.0f / 0.9f) : 0.0f;
        v[j] = bf16b(xd);
    }
    *reinterpret_cast<short8*>(bfrag + (size_t)c * 8) = v;
}

__global__ void __launch_bounds__(64, 2) gemm_kernel(const float* __restrict__ adj,
                                                     const short* __restrict__ bfrag,
                                                     float* __restrict__ out) {
    __shared__ char smem[2 * CHUNK];   // 10240 B, wave-private (1 wave/block)
    char* c0 = smem;
    char* c1 = smem + CHUNK;

    const int lane = threadIdx.x & 63;
    const int r    = lane & 15;        // MFMA A-row / output col
    const int kg   = lane >> 4;        // MFMA k-group
    const int row0 = blockIdx.x * MT;

    // A-load: instr (U,g) loads row U*2+g's [T*256 + lane*4 .. +3] -> 1KB/instr
    const float* abase = adj + (size_t)row0 * NN + (size_t)lane * 4;
    // STASH: lane's 4 floats are k0 = lane*4 of row g. Decompose:
    //   u=lane>>4 (sub-chunk), s=(lane&15)>>3, kg'=(lane&7)>>1, half=lane&1
    const int sbyte = (lane >> 4) * 1280 + ((lane & 15) >> 3) * 640 +
                      ((lane & 7) >> 1) * 16 + (lane & 1) * 8;
    // A-frag read: row r&7 (rows 8-15 of the MFMA tile duplicate 0-7)
    const int aoff  = (r & 7) * 80 + kg * 16;   // + U*1280 + s*640

    const short* bpA = bfrag + (size_t)lane * 8;   // even sub-phases
    const short* bpB = bpA + 4096;                 // odd sub-phases

    floatx4 Sa[8], Sb[8];
    short8  Ba[8], Bb[8];

#define ISSUE_A2(RA, TT, U)                                                    \
    {                                                                          \
        _Pragma("unroll")                                                      \
        for (int g = 0; g < 2; ++g)                                            \
            RA[(U) * 2 + g] = __builtin_nontemporal_load(                      \
                reinterpret_cast<const floatx4*>(                              \
                    abase + (size_t)((U) * 2 + g) * NN + (size_t)(TT) * APH)); \
        asm volatile("" ::: "memory");                                         \
    }

#define ISSUE_B(RB, BP)                                                       \
    {                                                                         \
        _Pragma("unroll")                                                     \
        for (int s = 0; s < 2; ++s)                                           \
            _Pragma("unroll")                                                 \
            for (int f = 0; f < 4; ++f)                                       \
                RB[s * 4 + f] =                                               \
                    *reinterpret_cast<const short8*>(BP + s * 2048 + f * 512);\
        BP += 8192;                                                           \
        asm volatile("" ::: "memory");                                        \
    }

#define STASH(RA, C)                                                         \
    {                                                                        \
        _Pragma("unroll")                                                    \
        for (int g = 0; g < 8; ++g) {                                       \
            short4v w_;                                                      \
            w_.x = bf16b(RA[g].x); w_.y = bf16b(RA[g].y);                    \
            w_.z = bf16b(RA[g].z); w_.w = bf16b(RA[g].w);                    \
            *reinterpret_cast<short4v*>((C) + sbyte + g * 80) = w_;          \
        }                                                                    \
    }

    floatx4 acc0 = {0.f, 0.f, 0.f, 0.f};
    floatx4 acc1 = {0.f, 0.f, 0.f, 0.f};
    floatx4 acc2 = {0.f, 0.f, 0.f, 0.f};
    floatx4 acc3 = {0.f, 0.f, 0.f, 0.f};

#define COMPUTE(C, RB, U)                                                         \
    {                                                                             \
        _Pragma("unroll")                                                         \
        for (int s = 0; s < 2; ++s) {                                             \
            short8 af = *reinterpret_cast<const short8*>(                         \
                (C) + aoff + (U) * 1280 + s * 640);                               \
            acc0 = __builtin_amdgcn_mfma_f32_16x16x32_bf16(af, RB[s*4+0], acc0, 0, 0, 0); \
            acc1 = __builtin_amdgcn_mfma_f32_16x16x32_bf16(af, RB[s*4+1], acc1, 0, 0, 0); \
            acc2 = __builtin_amdgcn_mfma_f32_16x16x32_bf16(af, RB[s*4+2], acc2, 0, 0, 0); \
            acc3 = __builtin_amdgcn_mfma_f32_16x16x32_bf16(af, RB[s*4+3], acc3, 0, 0, 0); \
        }                                                                         \
    }

    // prologue: A(0) full -> Sa; B(0),B(1); A(1) full -> Sb; stash A(0)
    ISSUE_A2(Sa, 0, 0); ISSUE_A2(Sa, 0, 1); ISSUE_A2(Sa, 0, 2); ISSUE_A2(Sa, 0, 3);
    ISSUE_B(Ba, bpA); ISSUE_B(Bb, bpB);
    ISSUE_A2(Sb, 1, 0); ISSUE_A2(Sb, 1, 1); ISSUE_A2(Sb, 1, 2); ISSUE_A2(Sb, 1, 3);
    STASH(Sa, c0);   // waits Sa (oldest); Sb + B stay outstanding

    for (int T = 0; T < NAPH; T += 2) {
        // phase T (even): compute c0; issue A(T+2) groups into Sa; stash A(T+1)
        COMPUTE(c0, Ba, 0); if (T + 2 < NAPH) ISSUE_A2(Sa, T + 2, 0); if (4*T + 2 < 256) ISSUE_B(Ba, bpA);
        COMPUTE(c0, Bb, 1); if (T + 2 < NAPH) ISSUE_A2(Sa, T + 2, 1); if (4*T + 3 < 256) ISSUE_B(Bb, bpB);
        COMPUTE(c0, Ba, 2); if (T + 2 < NAPH) ISSUE_A2(Sa, T + 2, 2); if (4*T + 4 < 256) ISSUE_B(Ba, bpA);
        COMPUTE(c0, Bb, 3); if (T + 2 < NAPH) ISSUE_A2(Sa, T + 2, 3); if (4*T + 5 < 256) ISSUE_B(Bb, bpB);
        if (T + 1 < NAPH) STASH(Sb, c1);   // A(T+1); A(T+2)+B newer, stay out

        // phase T+1 (odd): compute c1; issue A(T+3) into Sb; stash A(T+2)
        COMPUTE(c1, Ba, 0); if (T + 3 < NAPH) ISSUE_A2(Sb, T + 3, 0); if (4*T + 6 < 256) ISSUE_B(Ba, bpA);
        COMPUTE(c1, Bb, 1); if (T + 3 < NAPH) ISSUE_A2(Sb, T + 3, 1); if (4*T + 7 < 256) ISSUE_B(Bb, bpB);
        COMPUTE(c1, Ba, 2); if (T + 3 < NAPH) ISSUE_A2(Sb, T + 3, 2); if (4*T + 8 < 256) ISSUE_B(Ba, bpA);
        COMPUTE(c1, Bb, 3); if (T + 3 < NAPH) ISSUE_A2(Sb, T + 3, 3); if (4*T + 9 < 256) ISSUE_B(Bb, bpB);
        if (T + 2 < NAPH) STASH(Sa, c0);   // A(T+2)
    }

    // C/D: col(N) = r, row(M) = kg*4 + j (verified r1-r10).
    // MT=8: rows 8-15 are duplicates of 0-7 -> only kg<2 lanes store (rows 0-7).
    if (kg < 2) {
        const int orow = row0 + kg * 4;
        float* op = out + (size_t)orow * DD + r;
#pragma unroll
        for (int j = 0; j < 4; ++j) {
            op[(size_t)j * DD + 0]  = acc0[j];
            op[(size_t)j * DD + 16] = acc1[j];
            op[(size_t)j * DD + 32] = acc2[j];
            op[(size_t)j * DD + 48] = acc3[j];
        }
    }
}

extern "C" void kernel_launch(void* const* d_in, const int* in_sizes, int n_in,
                              void* d_out, int out_size, void* d_ws, size_t ws_size,
                              hipStream_t stream) {
    const float* x   = (const float*)d_in[0];
    const float* adj = (const float*)d_in[1];
    const float* u   = (const float*)d_in[2];
    float* out = (float*)d_out;
    short* bfrag = (short*)d_ws;   // 16384*64 bf16 = 2 MB

    prep_kernel<<<dim3(512), dim3(256), 0, stream>>>(x, u, bfrag);
    gemm_kernel<<<dim3(NN / MT), dim3(64), 0, stream>>>(adj, bfrag, out);
}

// Round 12
// 206.105 us; speedup vs baseline: 1.4875x; 1.4875x over previous
//
#include <hip/hip_runtime.h>
#include <hip/hip_bf16.h>

// LightGCN layer: out = adj @ (x * (u >= 0.1) / 0.9)
// x: [16384,64] f32, adj: [16384,16384] f32, u: [16384,64] f32, out: [16384,64] f32
//
// Round 12: RESTORE r10 (best, 205.8us) byte-identically after r11's MT=8
// regression (306us: doubling waves doubled per-CU issue work + B traffic ->
// issue-bound). r10 = 1KB-contiguous nt A-loads, barrier-free 1-wave blocks,
// counted-vmcnt 2-deep pipeline, B-in-regs as MFMA fragments.
// This is the pattern optimum: ~88% of the 6.29 TB/s copy ceiling.

#define NN 16384
#define DD 64
#define MT 16
#define APH 256                // A-phase: K floats per staged chunk
#define NAPH (NN / APH)        // 64 A-phases
#define CHUNK 10240            // 4 sub-chunks x 2560 B

typedef __attribute__((ext_vector_type(4))) float floatx4;
typedef __attribute__((ext_vector_type(4))) short short4v;
typedef __attribute__((ext_vector_type(8))) short short8;

static __device__ __forceinline__ short bf16b(float f) {
    union { __hip_bfloat16 h; short s; } cv;
    cv.h = __float2bfloat16(f);
    return cv.s;
}

// B in MFMA fragment-linear order (unchanged, verified r1-r10):
// chunk c = s*256 + f*64 + lane; shorts at c*8:
// element j = B[s*32 + (lane>>4)*8 + j][f*16 + (lane&15)]
__global__ void __launch_bounds__(256) prep_kernel(const float* __restrict__ x,
                                                   const float* __restrict__ u,
                                                   short* __restrict__ bfrag) {
    int c = blockIdx.x * 256 + threadIdx.x;
    int lane = c & 63;
    int f = (c >> 6) & 3;
    int s = c >> 8;
    int col = f * 16 + (lane & 15);
    int k0 = s * 32 + (lane >> 4) * 8;
    short8 v;
#pragma unroll
    for (int j = 0; j < 8; ++j) {
        int idx = (k0 + j) * DD + col;
        float xv = x[idx];
        float uv = u[idx];
        float xd = (uv >= 0.1f) ? xv * (1.0f / 0.9f) : 0.0f;
        v[j] = bf16b(xd);
    }
    *reinterpret_cast<short8*>(bfrag + (size_t)c * 8) = v;
}

__global__ void __launch_bounds__(64) gemm_kernel(const float* __restrict__ adj,
                                                  const short* __restrict__ bfrag,
                                                  float* __restrict__ out) {
    __shared__ char smem[2 * CHUNK];   // 20480 B, wave-private (1 wave/block)
    char* c0 = smem;
    char* c1 = smem + CHUNK;

    const int lane = threadIdx.x & 63;
    const int r    = lane & 15;        // MFMA A-row / output col
    const int kg   = lane >> 4;        // MFMA k-group
    const int row0 = blockIdx.x * MT;

    // A-load: instr g loads row g's [T*256 + lane*4 .. +3] -> 1KB contiguous/instr
    const float* abase = adj + (size_t)row0 * NN + (size_t)lane * 4;
    // STASH: lane's 4 floats are k0 = lane*4 of row g. Decompose k0:
    //   u=lane>>4 (sub-chunk), s=(lane&15)>>3, kg'=(lane&7)>>1, half=lane&1
    const int sbyte = (lane >> 4) * 2560 + ((lane & 15) >> 3) * 1280 +
                      ((lane & 7) >> 1) * 16 + (lane & 1) * 8;
    const int aoff  = r * 80 + kg * 16;   // A-frag read (+ u*2560 + s*1280)

    const short* bpA = bfrag + (size_t)lane * 8;   // even sub-phases
    const short* bpB = bpA + 4096;                 // odd sub-phases

    floatx4 Sa[16], Sb[16];
    short8  Ba[8], Bb[8];

#define ISSUE_A4(RA, TT, U)                                                    \
    {                                                                          \
        _Pragma("unroll")                                                      \
        for (int g = 0; g < 4; ++g)                                            \
            RA[(U) * 4 + g] = __builtin_nontemporal_load(                      \
                reinterpret_cast<const floatx4*>(                              \
                    abase + (size_t)((U) * 4 + g) * NN + (size_t)(TT) * APH)); \
        asm volatile("" ::: "memory");                                         \
    }

#define ISSUE_B(RB, BP)                                                       \
    {                                                                         \
        _Pragma("unroll")                                                     \
        for (int s = 0; s < 2; ++s)                                           \
            _Pragma("unroll")                                                 \
            for (int f = 0; f < 4; ++f)                                       \
                RB[s * 4 + f] =                                               \
                    *reinterpret_cast<const short8*>(BP + s * 2048 + f * 512);\
        BP += 8192;                                                           \
        asm volatile("" ::: "memory");                                        \
    }

#define STASH(RA, C)                                                         \
    {                                                                        \
        _Pragma("unroll")                                                    \
        for (int g = 0; g < 16; ++g) {                                       \
            short4v w_;                                                      \
            w_.x = bf16b(RA[g].x); w_.y = bf16b(RA[g].y);                    \
            w_.z = bf16b(RA[g].z); w_.w = bf16b(RA[g].w);                    \
            *reinterpret_cast<short4v*>((C) + sbyte + g * 80) = w_;          \
        }                                                                    \
    }

    floatx4 acc0 = {0.f, 0.f, 0.f, 0.f};
    floatx4 acc1 = {0.f, 0.f, 0.f, 0.f};
    floatx4 acc2 = {0.f, 0.f, 0.f, 0.f};
    floatx4 acc3 = {0.f, 0.f, 0.f, 0.f};

#define COMPUTE(C, RB, U)                                                         \
    {                                                                             \
        _Pragma("unroll")                                                         \
        for (int s = 0; s < 2; ++s) {                                             \
            short8 af = *reinterpret_cast<const short8*>(                         \
                (C) + aoff + (U) * 2560 + s * 1280);                              \
            acc0 = __builtin_amdgcn_mfma_f32_16x16x32_bf16(af, RB[s*4+0], acc0, 0, 0, 0); \
            acc1 = __builtin_amdgcn_mfma_f32_16x16x32_bf16(af, RB[s*4+1], acc1, 0, 0, 0); \
            acc2 = __builtin_amdgcn_mfma_f32_16x16x32_bf16(af, RB[s*4+2], acc2, 0, 0, 0); \
            acc3 = __builtin_amdgcn_mfma_f32_16x16x32_bf16(af, RB[s*4+3], acc3, 0, 0, 0); \
        }                                                                         \
    }

    // prologue: A(0) full -> Sa; B(0),B(1); A(1) full -> Sb; stash A(0)
    ISSUE_A4(Sa, 0, 0); ISSUE_A4(Sa, 0, 1); ISSUE_A4(Sa, 0, 2); ISSUE_A4(Sa, 0, 3);
    ISSUE_B(Ba, bpA); ISSUE_B(Bb, bpB);
    ISSUE_A4(Sb, 1, 0); ISSUE_A4(Sb, 1, 1); ISSUE_A4(Sb, 1, 2); ISSUE_A4(Sb, 1, 3);
    STASH(Sa, c0);   // waits Sa (oldest); Sb + B stay outstanding

    for (int T = 0; T < NAPH; T += 2) {
        // phase T (even): compute c0; issue A(T+2) groups into Sa; stash A(T+1)
        COMPUTE(c0, Ba, 0); if (T + 2 < NAPH) ISSUE_A4(Sa, T + 2, 0); if (4*T + 2 < 256) ISSUE_B(Ba, bpA);
        COMPUTE(c0, Bb, 1); if (T + 2 < NAPH) ISSUE_A4(Sa, T + 2, 1); if (4*T + 3 < 256) ISSUE_B(Bb, bpB);
        COMPUTE(c0, Ba, 2); if (T + 2 < NAPH) ISSUE_A4(Sa, T + 2, 2); if (4*T + 4 < 256) ISSUE_B(Ba, bpA);
        COMPUTE(c0, Bb, 3); if (T + 2 < NAPH) ISSUE_A4(Sa, T + 2, 3); if (4*T + 5 < 256) ISSUE_B(Bb, bpB);
        if (T + 1 < NAPH) STASH(Sb, c1);   // A(T+1); A(T+2)+B newer, stay out

        // phase T+1 (odd): compute c1; issue A(T+3) into Sb; stash A(T+2)
        COMPUTE(c1, Ba, 0); if (T + 3 < NAPH) ISSUE_A4(Sb, T + 3, 0); if (4*T + 6 < 256) ISSUE_B(Ba, bpA);
        COMPUTE(c1, Bb, 1); if (T + 3 < NAPH) ISSUE_A4(Sb, T + 3, 1); if (4*T + 7 < 256) ISSUE_B(Bb, bpB);
        COMPUTE(c1, Ba, 2); if (T + 3 < NAPH) ISSUE_A4(Sb, T + 3, 2); if (4*T + 8 < 256) ISSUE_B(Ba, bpA);
        COMPUTE(c1, Bb, 3); if (T + 3 < NAPH) ISSUE_A4(Sb, T + 3, 3); if (4*T + 9 < 256) ISSUE_B(Bb, bpB);
        if (T + 2 < NAPH) STASH(Sa, c0);   // A(T+2)
    }

    // C/D: col(N) = r, row(M) = kg*4 + j  (verified r1-r10)
    const int orow = row0 + kg * 4;
    float* op = out + (size_t)orow * DD + r;
#pragma unroll
    for (int j = 0; j < 4; ++j) {
        op[(size_t)j * DD + 0]  = acc0[j];
        op[(size_t)j * DD + 16] = acc1[j];
        op[(size_t)j * DD + 32] = acc2[j];
        op[(size_t)j * DD + 48] = acc3[j];
    }
}

extern "C" void kernel_launch(void* const* d_in, const int* in_sizes, int n_in,
                              void* d_out, int out_size, void* d_ws, size_t ws_size,
                              hipStream_t stream) {
    const float* x   = (const float*)d_in[0];
    const float* adj = (const float*)d_in[1];
    const float* u   = (const float*)d_in[2];
    float* out = (float*)d_out;
    short* bfrag = (short*)d_ws;   // 16384*64 bf16 = 2 MB

    prep_kernel<<<dim3(512), dim3(256), 0, stream>>>(x, u, bfrag);
    gemm_kernel<<<dim3(NN / MT), dim3(64), 0, stream>>>(adj, bfrag, out);
}